// Round 3
// baseline (357.537 us; speedup 1.0000x reference)
//
#include <hip/hip_runtime.h>

// WeldonPool2d: x[32,2048,32,32] fp32 -> out[32,2048] fp32
// out = (mean(top10 of 1024) + mean(bottom10 of 1024)) / 2 per row.
// One wave64 per row; 16 elems/lane; Batcher sort-16 in registers;
// 10x tournament extraction with DPP wave reductions (no LDS).

#define NROW 1024
#define WPB  4      // waves (rows) per 256-thread block
#define KSEL 10

#define CE(a,b) { float _lo = fminf(v[a], v[b]); float _hi = fmaxf(v[a], v[b]); v[a] = _lo; v[b] = _hi; }

// DPP reduce step: invalid lanes keep old (=own value), harmless for max/min.
#define DPP_STEP(x, ctrl, OP) { \
    int _xi = __float_as_int(x); \
    int _yi = __builtin_amdgcn_update_dpp(_xi, _xi, ctrl, 0xf, 0xf, false); \
    x = OP(x, __int_as_float(_yi)); }

// row_shr:1,2,4,8 then row_bcast15, row_bcast31 -> lane 63 holds full-wave result
#define WAVE_RED(x, OP) \
    DPP_STEP(x, 0x111, OP) \
    DPP_STEP(x, 0x112, OP) \
    DPP_STEP(x, 0x114, OP) \
    DPP_STEP(x, 0x118, OP) \
    DPP_STEP(x, 0x142, OP) \
    DPP_STEP(x, 0x143, OP)

__global__ __launch_bounds__(256, 4)
void weldon_pool2d_kernel(const float* __restrict__ x,
                          float* __restrict__ out, int nrows) {
    const int lane = (int)(threadIdx.x & 63u);
    const int wave = (int)(threadIdx.x >> 6u);
    const int row  = (int)blockIdx.x * WPB + wave;
    if (row >= nrows) return;

    // Coalesced: each float4 load has lanes 0..63 reading consecutive 16B chunks.
    const float4* p = reinterpret_cast<const float4*>(x) + (size_t)row * (NROW / 4);
    float4 A = p[lane];
    float4 B = p[lane + 64];
    float4 C = p[lane + 128];
    float4 D = p[lane + 192];

    float v[16] = {A.x, A.y, A.z, A.w, B.x, B.y, B.z, B.w,
                   C.x, C.y, C.z, C.w, D.x, D.y, D.z, D.w};

    // Batcher odd-even mergesort for 16 (ascending), 63 compare-exchanges.
    CE(0,1) CE(2,3) CE(4,5) CE(6,7) CE(8,9) CE(10,11) CE(12,13) CE(14,15)
    CE(0,2) CE(1,3) CE(4,6) CE(5,7) CE(8,10) CE(9,11) CE(12,14) CE(13,15)
    CE(1,2) CE(5,6) CE(9,10) CE(13,14)
    CE(0,4) CE(1,5) CE(2,6) CE(3,7) CE(8,12) CE(9,13) CE(10,14) CE(11,15)
    CE(2,4) CE(3,5) CE(10,12) CE(11,13)
    CE(1,2) CE(3,4) CE(5,6) CE(9,10) CE(11,12) CE(13,14)
    CE(0,8) CE(1,9) CE(2,10) CE(3,11) CE(4,12) CE(5,13) CE(6,14) CE(7,15)
    CE(4,8) CE(5,9) CE(6,10) CE(7,11)
    CE(2,4) CE(3,5) CE(6,8) CE(7,9) CE(10,12) CE(11,13)
    CE(1,2) CE(3,4) CE(5,6) CE(7,8) CE(9,10) CE(11,12) CE(13,14)

    // Per-lane candidate lists (only constant indices -> stays in VGPRs).
    float t[10] = {v[15],v[14],v[13],v[12],v[11],v[10],v[9],v[8],v[7],v[6]};
    float b[10] = {v[0],v[1],v[2],v[3],v[4],v[5],v[6],v[7],v[8],v[9]};

    float tsum = 0.f, bsum = 0.f;
    #pragma unroll
    for (int it = 0; it < KSEL; ++it) {
        // Global max of per-lane heads (largest remaining element overall).
        float hx = t[0];
        WAVE_RED(hx, fmaxf)
        float mx = __int_as_float(__builtin_amdgcn_readlane(__float_as_int(hx), 63));
        // Global min of per-lane heads.
        float hn = b[0];
        WAVE_RED(hn, fminf)
        float mn = __int_as_float(__builtin_amdgcn_readlane(__float_as_int(hn), 63));

        tsum += mx;   // uniform across lanes; summed in descending order (matches ref)
        bsum += mn;   // ascending order (matches ref's top_k(-x))

        // Exactly one lane removes one instance of the extracted value.
        unsigned long long bmx = __ballot(t[0] == mx);
        if (lane == (int)(__ffsll((long long)bmx) - 1)) {
            t[0]=t[1]; t[1]=t[2]; t[2]=t[3]; t[3]=t[4]; t[4]=t[5];
            t[5]=t[6]; t[6]=t[7]; t[7]=t[8]; t[8]=t[9];
            t[9] = -__builtin_inff();
        }
        unsigned long long bmn = __ballot(b[0] == mn);
        if (lane == (int)(__ffsll((long long)bmn) - 1)) {
            b[0]=b[1]; b[1]=b[2]; b[2]=b[3]; b[3]=b[4]; b[4]=b[5];
            b[5]=b[6]; b[6]=b[7]; b[7]=b[8]; b[8]=b[9];
            b[9] = __builtin_inff();
        }
    }

    if (lane == 0) {
        out[row] = (tsum / (float)KSEL + bsum / (float)KSEL) * 0.5f;
    }
}

extern "C" void kernel_launch(void* const* d_in, const int* in_sizes, int n_in,
                              void* d_out, int out_size, void* d_ws, size_t ws_size,
                              hipStream_t stream) {
    const float* x = (const float*)d_in[0];
    float* out = (float*)d_out;
    const int nrows = out_size;                 // 32*2048 = 65536 rows of 1024
    const int blocks = (nrows + WPB - 1) / WPB; // exact: 16384
    weldon_pool2d_kernel<<<blocks, 64 * WPB, 0, stream>>>(x, out, nrows);
}

// Round 4
// 357.330 us; speedup vs baseline: 1.0006x; 1.0006x over previous
//
#include <hip/hip_runtime.h>

// WeldonPool2d: x[32,2048,32,32] fp32 -> out[32,2048] fp32
// out = (mean(top10 of 1024) + mean(bottom10 of 1024)) / 2 per row.
// One wave64 per row; 16 elems/lane; Batcher sort-16 in registers;
// 10x tournament extraction with DPP wave reductions (no LDS).
// R4: __launch_bounds__(256,8) pins 8 waves/SIMD (occupancy probe);
//     branchless cndmask removal replaces divergent exec-mask shifts.

#define NROW 1024
#define WPB  4      // waves (rows) per 256-thread block
#define KSEL 10

#define CE(a,b) { float _lo = fminf(v[a], v[b]); float _hi = fmaxf(v[a], v[b]); v[a] = _lo; v[b] = _hi; }

// DPP reduce step: invalid lanes keep old (=own value), harmless for max/min.
#define DPP_STEP(x, ctrl, OP) { \
    int _xi = __float_as_int(x); \
    int _yi = __builtin_amdgcn_update_dpp(_xi, _xi, ctrl, 0xf, 0xf, false); \
    x = OP(x, __int_as_float(_yi)); }

// row_shr:1,2,4,8 then row_bcast15, row_bcast31 -> lane 63 holds full-wave result
#define WAVE_RED(x, OP) \
    DPP_STEP(x, 0x111, OP) \
    DPP_STEP(x, 0x112, OP) \
    DPP_STEP(x, 0x114, OP) \
    DPP_STEP(x, 0x118, OP) \
    DPP_STEP(x, 0x142, OP) \
    DPP_STEP(x, 0x143, OP)

__global__ __launch_bounds__(256, 8)
void weldon_pool2d_kernel(const float* __restrict__ x,
                          float* __restrict__ out, int nrows) {
    const int lane = (int)(threadIdx.x & 63u);
    const int wave = (int)(threadIdx.x >> 6u);
    const int row  = (int)blockIdx.x * WPB + wave;
    if (row >= nrows) return;

    // Coalesced: each float4 load has lanes 0..63 reading consecutive 16B chunks.
    const float4* p = reinterpret_cast<const float4*>(x) + (size_t)row * (NROW / 4);
    float4 A = p[lane];
    float4 B = p[lane + 64];
    float4 C = p[lane + 128];
    float4 D = p[lane + 192];

    float v[16] = {A.x, A.y, A.z, A.w, B.x, B.y, B.z, B.w,
                   C.x, C.y, C.z, C.w, D.x, D.y, D.z, D.w};

    // Batcher odd-even mergesort for 16 (ascending), 63 compare-exchanges.
    CE(0,1) CE(2,3) CE(4,5) CE(6,7) CE(8,9) CE(10,11) CE(12,13) CE(14,15)
    CE(0,2) CE(1,3) CE(4,6) CE(5,7) CE(8,10) CE(9,11) CE(12,14) CE(13,15)
    CE(1,2) CE(5,6) CE(9,10) CE(13,14)
    CE(0,4) CE(1,5) CE(2,6) CE(3,7) CE(8,12) CE(9,13) CE(10,14) CE(11,15)
    CE(2,4) CE(3,5) CE(10,12) CE(11,13)
    CE(1,2) CE(3,4) CE(5,6) CE(9,10) CE(11,12) CE(13,14)
    CE(0,8) CE(1,9) CE(2,10) CE(3,11) CE(4,12) CE(5,13) CE(6,14) CE(7,15)
    CE(4,8) CE(5,9) CE(6,10) CE(7,11)
    CE(2,4) CE(3,5) CE(6,8) CE(7,9) CE(10,12) CE(11,13)
    CE(1,2) CE(3,4) CE(5,6) CE(7,8) CE(9,10) CE(11,12) CE(13,14)

    // Per-lane candidate lists (only constant indices -> stays in VGPRs).
    float t[10] = {v[15],v[14],v[13],v[12],v[11],v[10],v[9],v[8],v[7],v[6]};
    float b[10] = {v[0],v[1],v[2],v[3],v[4],v[5],v[6],v[7],v[8],v[9]};

    const float NINF = -__builtin_inff();
    const float PINF =  __builtin_inff();

    float tsum = 0.f, bsum = 0.f;
    #pragma unroll
    for (int it = 0; it < KSEL; ++it) {
        // Global max of per-lane heads (largest remaining element overall).
        float hx = t[0];
        WAVE_RED(hx, fmaxf)
        float mx = __int_as_float(__builtin_amdgcn_readlane(__float_as_int(hx), 63));
        // Global min of per-lane heads.
        float hn = b[0];
        WAVE_RED(hn, fminf)
        float mn = __int_as_float(__builtin_amdgcn_readlane(__float_as_int(hn), 63));

        tsum += mx;   // uniform across lanes; summed in descending order (matches ref)
        bsum += mn;   // ascending order (matches ref's top_k(-x))

        // Branchless: exactly one lane (lowest-index tie) shifts its list.
        unsigned long long bmx = __ballot(t[0] == mx);
        bool winT = (lane == (int)(__ffsll((long long)bmx) - 1));
        t[0] = winT ? t[1] : t[0];
        t[1] = winT ? t[2] : t[1];
        t[2] = winT ? t[3] : t[2];
        t[3] = winT ? t[4] : t[3];
        t[4] = winT ? t[5] : t[4];
        t[5] = winT ? t[6] : t[5];
        t[6] = winT ? t[7] : t[6];
        t[7] = winT ? t[8] : t[7];
        t[8] = winT ? t[9] : t[8];
        t[9] = winT ? NINF : t[9];

        unsigned long long bmn = __ballot(b[0] == mn);
        bool winB = (lane == (int)(__ffsll((long long)bmn) - 1));
        b[0] = winB ? b[1] : b[0];
        b[1] = winB ? b[2] : b[1];
        b[2] = winB ? b[3] : b[2];
        b[3] = winB ? b[4] : b[3];
        b[4] = winB ? b[5] : b[4];
        b[5] = winB ? b[6] : b[5];
        b[6] = winB ? b[7] : b[6];
        b[7] = winB ? b[8] : b[7];
        b[8] = winB ? b[9] : b[8];
        b[9] = winB ? PINF : b[9];
    }

    if (lane == 0) {
        out[row] = (tsum / (float)KSEL + bsum / (float)KSEL) * 0.5f;
    }
}

extern "C" void kernel_launch(void* const* d_in, const int* in_sizes, int n_in,
                              void* d_out, int out_size, void* d_ws, size_t ws_size,
                              hipStream_t stream) {
    const float* x = (const float*)d_in[0];
    float* out = (float*)d_out;
    const int nrows = out_size;                 // 32*2048 = 65536 rows of 1024
    const int blocks = (nrows + WPB - 1) / WPB; // exact: 16384
    weldon_pool2d_kernel<<<blocks, 64 * WPB, 0, stream>>>(x, out, nrows);
}